// Round 15
// baseline (31.889 us; speedup 1.0000x reference)
//
#include <hip/hip_runtime.h>
#include <math.h>

#define B_TOTAL 16384
#define NQ 512
#define NUM 3
#define NWAVES 8192   // 2048 blocks * 4 waves; each wave owns 2 batches

typedef unsigned u32;

// DPP wave reduces (R13/R14-validated exact): pure VALU, no LDS pipe.
__device__ __forceinline__ u32 wave_umax_dpp(u32 v) {
    u32 r = v, t;
    t = (u32)__builtin_amdgcn_update_dpp(0, (int)r, 0x111, 0xF, 0xF, false);
    r = t > r ? t : r;   // row_shr:1
    t = (u32)__builtin_amdgcn_update_dpp(0, (int)r, 0x112, 0xF, 0xF, false);
    r = t > r ? t : r;   // row_shr:2
    t = (u32)__builtin_amdgcn_update_dpp(0, (int)r, 0x114, 0xF, 0xF, false);
    r = t > r ? t : r;   // row_shr:4
    t = (u32)__builtin_amdgcn_update_dpp(0, (int)r, 0x118, 0xF, 0xF, false);
    r = t > r ? t : r;   // row_shr:8
    t = (u32)__builtin_amdgcn_update_dpp(0, (int)r, 0x142, 0xF, 0xF, false);
    r = t > r ? t : r;   // row_bcast:15
    t = (u32)__builtin_amdgcn_update_dpp(0, (int)r, 0x143, 0xF, 0xF, false);
    r = t > r ? t : r;   // row_bcast:31
    return (u32)__builtin_amdgcn_readlane((int)r, 63);  // wave-uniform
}

__device__ __forceinline__ u32 wave_umin_dpp(u32 v) {
    u32 r = v, t;
    t = (u32)__builtin_amdgcn_update_dpp(-1, (int)r, 0x111, 0xF, 0xF, false);
    r = t < r ? t : r;
    t = (u32)__builtin_amdgcn_update_dpp(-1, (int)r, 0x112, 0xF, 0xF, false);
    r = t < r ? t : r;
    t = (u32)__builtin_amdgcn_update_dpp(-1, (int)r, 0x114, 0xF, 0xF, false);
    r = t < r ? t : r;
    t = (u32)__builtin_amdgcn_update_dpp(-1, (int)r, 0x118, 0xF, 0xF, false);
    r = t < r ? t : r;
    t = (u32)__builtin_amdgcn_update_dpp(-1, (int)r, 0x142, 0xF, 0xF, false);
    r = t < r ? t : r;
    t = (u32)__builtin_amdgcn_update_dpp(-1, (int)r, 0x143, 0xF, 0xF, false);
    r = t < r ? t : r;
    return (u32)__builtin_amdgcn_readlane((int)r, 63);  // wave-uniform
}

// Two batches per wave with fully interleaved dependent-load chains:
// if resident waves don't overlap each other's memory chains (R6..R14
// evidence), intra-wave ILP is the only remaining latency hider. Greedy
// algorithm/tie-break/guard-band identical to the validated R14 path.
__global__ __launch_bounds__(256) void greedy_nms_kernel(
    const float* __restrict__ conf,   // [B, NQ]
    const float* __restrict__ pos,    // [B, NQ, 3]
    float* __restrict__ out)          // [B, NUM, 3]
{
    const int lane = threadIdx.x & 63;
    const int wg = (blockIdx.x << 2) | (threadIdx.x >> 6);  // 0..NWAVES-1
    const int bA = wg;
    const int bB = wg + NWAVES;

    const float* pbA = pos + (size_t)bA * NQ * 3;
    const float* pbB = pos + (size_t)bB * NQ * 3;

    // both conf streams issued before any use (independent, coalesced)
    const float4* cA4 = reinterpret_cast<const float4*>(conf + (size_t)bA * NQ);
    const float4* cB4 = reinterpret_cast<const float4*>(conf + (size_t)bB * NQ);
    const float4 a0 = cA4[lane * 2 + 0];
    const float4 a1 = cA4[lane * 2 + 1];
    const float4 b0 = cB4[lane * 2 + 0];
    const float4 b1 = cB4[lane * 2 + 1];

    // monotone float->u32 keys; key 0 == consumed (no NaN/-inf in input)
    u32 kA[8], kB[8];
    {
        float fA[8] = {a0.x, a0.y, a0.z, a0.w, a1.x, a1.y, a1.z, a1.w};
        float fB[8] = {b0.x, b0.y, b0.z, b0.w, b1.x, b1.y, b1.z, b1.w};
        #pragma unroll
        for (int s = 0; s < 8; ++s) {
            int ia = __float_as_int(fA[s]);
            kA[s] = (u32)ia ^ ((u32)(ia >> 31) | 0x80000000u);
            int ib = __float_as_int(fB[s]);
            kB[s] = (u32)ib ^ ((u32)(ib >> 31) | 0x80000000u);
        }
    }

    // exact argmax (R14-validated): n = 8*lane+s; first-equal slot + umin
    // over n == reference's stable smaller-index tie-break.
    auto argmax_dpp = [&](u32 (&k)[8], u32& gm_out) -> int {
        u32 m = k[0];
        #pragma unroll
        for (int s = 1; s < 8; ++s) m = k[s] > m ? k[s] : m;
        const u32 gm = wave_umax_dpp(m);
        int im = 8;
        #pragma unroll
        for (int s = 7; s >= 0; --s)
            if (k[s] == gm) im = s;
        const u32 candn = (im < 8) ? (u32)((lane << 3) | im) : 0xFFFFFFFFu;
        const u32 n = wave_umin_dpp(candn);
        gm_out = gm;
        return (int)n;
    };

    auto consume = [&](u32 (&k)[8], int n) {
        const int ci = ((n >> 3) == lane) ? (n & 7) : 8;
        #pragma unroll
        for (int s = 0; s < 8; ++s)
            if (ci == s) k[s] = 0u;
    };

    const float TH  = 0.78539816339744830961f; // pi/4 (f32 == jnp thresh)
    const float CLO = 0.70710478f;             // cos(pi/4) - ~2e-6
    const float CHI = 0.70710878f;             // cos(pi/4) + ~2e-6

    auto passv = [&](float ax, float ay, float az,
                     float px, float py, float pz) -> bool {
        float d = fabsf(ax * px + ay * py + az * pz);
        if (d <= CLO) return true;                  // clearly >= pi/4
        if (d >= CHI) return false;                 // clearly <  pi/4
        return acosf(fminf(d, 1.f)) >= TH;          // exact at boundary
    };

    // ---- #1 for both batches; the two p1 loads overlap in flight ----
    u32 g;
    const int w1A = argmax_dpp(kA, g); consume(kA, w1A);
    const int w1B = argmax_dpp(kB, g); consume(kB, w1B);
    const float p1Ax = pbA[w1A * 3 + 0];
    const float p1Ay = pbA[w1A * 3 + 1];
    const float p1Az = pbA[w1A * 3 + 2];
    const float p1Bx = pbB[w1B * 3 + 0];
    const float p1By = pbB[w1B * 3 + 1];
    const float p1Bz = pbB[w1B * 3 + 2];

    // accepted-set state; zero vector auto-passes (masked-inf semantics)
    float a1Ax = 0.f, a1Ay = 0.f, a1Az = 0.f;
    float a1Bx = 0.f, a1By = 0.f, a1Bz = 0.f;
    float o2Ax = 0.f, o2Ay = 0.f, o2Az = 0.f;
    float o2Bx = 0.f, o2By = 0.f, o2Bz = 0.f;
    int cntA = 1, cntB = 1;
    bool runA = true, runB = true;

    #pragma unroll 1
    for (int it = 1; it < NQ && (runA || runB); ++it) {
        int nA = 0, nB = 0;
        u32 gmA = 0u, gmB = 0u;
        if (runA) nA = argmax_dpp(kA, gmA);
        if (runB) nB = argmax_dpp(kB, gmB);
        const bool actA = runA && (gmA != 0u);
        const bool actB = runB && (gmB != 0u);
        if (runA && gmA == 0u) runA = false;
        if (runB && gmB == 0u) runB = false;

        float pAx, pAy, pAz, pBx, pBy, pBz;
        if (actA) {                       // issue A's row load
            consume(kA, nA);
            pAx = pbA[nA * 3 + 0]; pAy = pbA[nA * 3 + 1]; pAz = pbA[nA * 3 + 2];
        }
        if (actB) {                       // issue B's row load (overlaps A's)
            consume(kB, nB);
            pBx = pbB[nB * 3 + 0]; pBy = pbB[nB * 3 + 1]; pBz = pbB[nB * 3 + 2];
        }

        if (actA) {
            const bool add = passv(p1Ax, p1Ay, p1Az, pAx, pAy, pAz) &&
                             passv(a1Ax, a1Ay, a1Az, pAx, pAy, pAz);
            if (add) {
                if (cntA == 1) {
                    o2Ax = pAx; o2Ay = pAy; o2Az = pAz;
                    a1Ax = pAx; a1Ay = pAy; a1Az = pAz;
                    cntA = 2;
                } else {                  // third accepted: emit now
                    if (lane == 0) {
                        float* ob = out + (size_t)bA * 9;
                        ob[0] = p1Ax; ob[1] = p1Ay; ob[2] = p1Az;
                        ob[3] = o2Ax; ob[4] = o2Ay; ob[5] = o2Az;
                        ob[6] = pAx;  ob[7] = pAy;  ob[8] = pAz;
                    }
                    cntA = 3; runA = false;
                }
            }
        }
        if (actB) {
            const bool add = passv(p1Bx, p1By, p1Bz, pBx, pBy, pBz) &&
                             passv(a1Bx, a1By, a1Bz, pBx, pBy, pBz);
            if (add) {
                if (cntB == 1) {
                    o2Bx = pBx; o2By = pBy; o2Bz = pBz;
                    a1Bx = pBx; a1By = pBy; a1Bz = pBz;
                    cntB = 2;
                } else {
                    if (lane == 0) {
                        float* ob = out + (size_t)bB * 9;
                        ob[0] = p1Bx; ob[1] = p1By; ob[2] = p1Bz;
                        ob[3] = o2Bx; ob[4] = o2By; ob[5] = o2Bz;
                        ob[6] = pBx;  ob[7] = pBy;  ob[8] = pBz;
                    }
                    cntB = 3; runB = false;
                }
            }
        }
    }

    // rare: fewer than 3 accepted -> remaining slots are pos[0] (ref default)
    if (cntA < 3) {
        const float p0x = pbA[0], p0y = pbA[1], p0z = pbA[2];
        const float q2x = (cntA >= 2) ? o2Ax : p0x;
        const float q2y = (cntA >= 2) ? o2Ay : p0y;
        const float q2z = (cntA >= 2) ? o2Az : p0z;
        if (lane == 0) {
            float* ob = out + (size_t)bA * 9;
            ob[0] = p1Ax; ob[1] = p1Ay; ob[2] = p1Az;
            ob[3] = q2x;  ob[4] = q2y;  ob[5] = q2z;
            ob[6] = p0x;  ob[7] = p0y;  ob[8] = p0z;
        }
    }
    if (cntB < 3) {
        const float p0x = pbB[0], p0y = pbB[1], p0z = pbB[2];
        const float q2x = (cntB >= 2) ? o2Bx : p0x;
        const float q2y = (cntB >= 2) ? o2By : p0y;
        const float q2z = (cntB >= 2) ? o2Bz : p0z;
        if (lane == 0) {
            float* ob = out + (size_t)bB * 9;
            ob[0] = p1Bx; ob[1] = p1By; ob[2] = p1Bz;
            ob[3] = q2x;  ob[4] = q2y;  ob[5] = q2z;
            ob[6] = p0x;  ob[7] = p0y;  ob[8] = p0z;
        }
    }
}

extern "C" void kernel_launch(void* const* d_in, const int* in_sizes, int n_in,
                              void* d_out, int out_size, void* d_ws, size_t ws_size,
                              hipStream_t stream) {
    const float* pred_logits = (const float*)d_in[0]; // [B, NQ, 1]
    const float* pred_pos    = (const float*)d_in[1]; // [B, NQ, 3]
    float* out = (float*)d_out;                       // [B, NUM, 3]

    greedy_nms_kernel<<<NWAVES / 4, 256, 0, stream>>>(pred_logits, pred_pos, out);
}

// Round 16
// 28.513 us; speedup vs baseline: 1.1184x; 1.1184x over previous
//
#include <hip/hip_runtime.h>
#include <math.h>

#define B_TOTAL 16384
#define NQ 512
#define NUM 3
#define TOPK 8

typedef unsigned u32;
typedef unsigned long long u64;

// 6-step DPP umax reduce -> lane 63 holds wave max (R13/R14-validated).
__device__ __forceinline__ u32 wave_umax_dpp(u32 v) {
    u32 r = v, t;
    t = (u32)__builtin_amdgcn_update_dpp(0, (int)r, 0x111, 0xF, 0xF, false);
    r = t > r ? t : r;   // row_shr:1
    t = (u32)__builtin_amdgcn_update_dpp(0, (int)r, 0x112, 0xF, 0xF, false);
    r = t > r ? t : r;   // row_shr:2
    t = (u32)__builtin_amdgcn_update_dpp(0, (int)r, 0x114, 0xF, 0xF, false);
    r = t > r ? t : r;   // row_shr:4
    t = (u32)__builtin_amdgcn_update_dpp(0, (int)r, 0x118, 0xF, 0xF, false);
    r = t > r ? t : r;   // row_shr:8
    t = (u32)__builtin_amdgcn_update_dpp(0, (int)r, 0x142, 0xF, 0xF, false);
    r = t > r ? t : r;   // row_bcast:15
    t = (u32)__builtin_amdgcn_update_dpp(0, (int)r, 0x143, 0xF, 0xF, false);
    r = t > r ? t : r;   // row_bcast:31
    return (u32)__builtin_amdgcn_readlane((int)r, 63);  // wave-uniform
}

__device__ __forceinline__ float bcastf(float v, int l) {
    return __int_as_float(__builtin_amdgcn_readlane(__float_as_int(v), l));
}

// One wave per batch, 4 waves/block, no LDS.
// The winner SEQUENCE (descending conf) is independent of the accept tests,
// so: extract ranks 0..7 with 8 chained DPP argmaxes (no loads in the
// chain; tie-break = ballot/ffs/readlane, exact stable smaller-index), and
// issue rank-i's pos row load the moment its index is known (lane i gathers
// it; the load flies during the remaining extraction). Two ballots resolve
// greedy #2/#3 over ranks 0..7 (~97.4% of batches). Rare exact fallback
// continues iteratively from rank 8 (R14-validated path, DPP argmax).
__global__ __launch_bounds__(256) void greedy_nms_kernel(
    const float* __restrict__ conf,   // [B, NQ]
    const float* __restrict__ pos,    // [B, NQ, 3]
    float* __restrict__ out)          // [B, NUM, 3]
{
    const int lane = threadIdx.x & 63;
    const int b = (blockIdx.x << 2) | (threadIdx.x >> 6);   // grid*4 == B

    const float* cb = conf + (size_t)b * NQ;
    const float* pb = pos  + (size_t)b * NQ * 3;

    // conf: lane owns elements 8l..8l+7 (two 1KB-coalesced float4 loads)
    const float4* cb4 = reinterpret_cast<const float4*>(cb);
    const float4 c0 = cb4[lane * 2 + 0];
    const float4 c1 = cb4[lane * 2 + 1];

    // monotone float->u32 keys; key 0 == consumed (no NaN/-inf in input)
    u32 k[8];
    {
        float f[8] = {c0.x, c0.y, c0.z, c0.w, c1.x, c1.y, c1.z, c1.w};
        #pragma unroll
        for (int s = 0; s < 8; ++s) {
            int bi = __float_as_int(f[s]);
            k[s] = (u32)bi ^ ((u32)(bi >> 31) | 0x80000000u);
        }
    }

    // exact argmax: DPP umax of local maxes -> gm; owner = first lane with
    // an equal slot (ballot+ffs), slot = its first equal slot; n = 8*owner
    // + slot == min index among maxima == reference stable tie-break.
    auto argmax_fast = [&](u32& gm_out) -> int {
        u32 m = k[0];
        #pragma unroll
        for (int s = 1; s < 8; ++s) m = k[s] > m ? k[s] : m;
        const u32 gm = wave_umax_dpp(m);
        int im = 8;
        #pragma unroll
        for (int s = 7; s >= 0; --s)
            if (k[s] == gm) im = s;                 // first equal slot
        const u64 ball = __ballot(im < 8);
        const int owner = __ffsll(ball) - 1;        // min lane
        const int oim = __builtin_amdgcn_readlane(im, owner);
        gm_out = gm;
        return (owner << 3) | oim;
    };

    auto consume = [&](int n) {
        const int ci = ((n >> 3) == lane) ? (n & 7) : 8;
        #pragma unroll
        for (int s = 0; s < 8; ++s)
            if (ci == s) k[s] = 0u;
    };

    // ---- extract ranks 0..7; lane i's row load issues at iteration i ----
    float gx = 0.f, gy = 0.f, gz = 0.f;   // rank-`lane` pos row (lanes 0..7)
    #pragma unroll
    for (int i = 0; i < TOPK; ++i) {
        u32 gm;
        const int n = argmax_fast(gm);    // gm>0 always: 512 real keys
        consume(n);
        if (lane == i) {
            gx = pb[n * 3 + 0];
            gy = pb[n * 3 + 1];
            gz = pb[n * 3 + 2];
        }
    }

    const float TH  = 0.78539816339744830961f; // pi/4 (f32 == jnp thresh)
    const float CLO = 0.70710478f;             // cos(pi/4) - ~2e-6
    const float CHI = 0.70710878f;             // cos(pi/4) + ~2e-6

    auto passv = [&](float ax, float ay, float az,
                     float px, float py, float pz) -> bool {
        float d = fabsf(ax * px + ay * py + az * pz);
        if (d <= CLO) return true;                  // clearly >= pi/4
        if (d >= CHI) return false;                 // clearly <  pi/4
        return acosf(fminf(d, 1.f)) >= TH;          // exact at boundary
    };

    // ---- greedy over ranks 0..7 via ballots ----
    const float p1x = bcastf(gx, 0), p1y = bcastf(gy, 0), p1z = bcastf(gz, 0);
    const u64 ball1 = __ballot(passv(p1x, p1y, p1z, gx, gy, gz)) & 0xFEull;

    float o2x, o2y, o2z;
    bool have2 = false;
    if (ball1 != 0) {
        const int i2 = __ffsll(ball1) - 1;
        o2x = bcastf(gx, i2); o2y = bcastf(gy, i2); o2z = bcastf(gz, i2);
        have2 = true;
        const u64 ball3 = ball1 & __ballot(passv(o2x, o2y, o2z, gx, gy, gz))
                                & ~((2ull << i2) - 1);
        if (ball3 != 0) {                           // fast path (~97.4%)
            const int i3 = __ffsll(ball3) - 1;
            const float o3x = bcastf(gx, i3);
            const float o3y = bcastf(gy, i3);
            const float o3z = bcastf(gz, i3);
            if (lane == 0) {
                float* ob = out + (size_t)b * 9;
                ob[0] = p1x; ob[1] = p1y; ob[2] = p1z;
                ob[3] = o2x; ob[4] = o2y; ob[5] = o2z;
                ob[6] = o3x; ob[7] = o3y; ob[8] = o3z;
            }
            return;
        }
    }

    // ---- rare exact fallback: continue iterative greedy from rank 8 ----
    const float p0x = pb[0], p0y = pb[1], p0z = pb[2];  // reference default
    float a1x = 0.f, a1y = 0.f, a1z = 0.f;   // zero vector auto-passes
    float o3x = p0x, o3y = p0y, o3z = p0z;
    int count = 1;
    if (have2) { a1x = o2x; a1y = o2y; a1z = o2z; count = 2; }
    else       { o2x = p0x; o2y = p0y; o2z = p0z; }

    #pragma unroll 1
    for (int it = TOPK; it < NQ; ++it) {
        u32 gm;
        const int n = argmax_fast(gm);
        if (gm == 0u) break;                        // keys exhausted
        consume(n);
        const float px = pb[n * 3 + 0];             // broadcast 1-line load
        const float py = pb[n * 3 + 1];
        const float pz = pb[n * 3 + 2];
        const bool add = passv(p1x, p1y, p1z, px, py, pz) &&
                         passv(a1x, a1y, a1z, px, py, pz);
        if (add) {
            if (count == 1) {
                o2x = px; o2y = py; o2z = pz;
                a1x = px; a1y = py; a1z = pz;
                count = 2;
            } else {
                o3x = px; o3y = py; o3z = pz;
                break;                              // third accepted
            }
        }
    }

    if (lane == 0) {
        float* ob = out + (size_t)b * 9;
        ob[0] = p1x; ob[1] = p1y; ob[2] = p1z;
        ob[3] = o2x; ob[4] = o2y; ob[5] = o2z;
        ob[6] = o3x; ob[7] = o3y; ob[8] = o3z;
    }
}

extern "C" void kernel_launch(void* const* d_in, const int* in_sizes, int n_in,
                              void* d_out, int out_size, void* d_ws, size_t ws_size,
                              hipStream_t stream) {
    const float* pred_logits = (const float*)d_in[0]; // [B, NQ, 1]
    const float* pred_pos    = (const float*)d_in[1]; // [B, NQ, 3]
    float* out = (float*)d_out;                       // [B, NUM, 3]

    const int grid = B_TOTAL / 4;                     // 4 waves/block
    greedy_nms_kernel<<<grid, 256, 0, stream>>>(pred_logits, pred_pos, out);
}

// Round 17
// 26.342 us; speedup vs baseline: 1.2106x; 1.0824x over previous
//
#include <hip/hip_runtime.h>
#include <math.h>

#define B_TOTAL 16384
#define NQ 512
#define NUM 3

// One wave per batch, 4 waves/block. R6/R10's masked-argmax algorithm
// (#1 = argmax conf; #2 = argmax among passers vs p1; #3 = passers vs p1&p2)
// with ALL cross-lane reductions done via DPP row ops (pure VALU, ~2-4 cy
// per step) instead of ds_bpermute shuffles (~35 cy, LDS pipe). The kernel
// contains zero ds_bpermute:
//   - argmax = DPP umax-reduce of keys -> readlane(63), then exact stable
//     tie-break via DPP umin-reduce of (first-equal-slot -> n = im*64+lane).
//   - winner n is wave-uniform (SGPR) -> get_row is a broadcast LDS read.
// Data path identical to R10: pos staged column-major to LDS (coalesced 1KB
// float4 bursts), element n = i*64+lane, conflict-free mask_keys reads.
// Session-best configuration (R13: 26.40 us, absmax 0) restored verbatim.
typedef unsigned u32;

__device__ __forceinline__ u32 wave_umax_dpp(u32 v) {
    u32 r = v, t;
    t = (u32)__builtin_amdgcn_update_dpp(0, (int)r, 0x111, 0xF, 0xF, false);
    r = t > r ? t : r;   // row_shr:1
    t = (u32)__builtin_amdgcn_update_dpp(0, (int)r, 0x112, 0xF, 0xF, false);
    r = t > r ? t : r;   // row_shr:2
    t = (u32)__builtin_amdgcn_update_dpp(0, (int)r, 0x114, 0xF, 0xF, false);
    r = t > r ? t : r;   // row_shr:4
    t = (u32)__builtin_amdgcn_update_dpp(0, (int)r, 0x118, 0xF, 0xF, false);
    r = t > r ? t : r;   // row_shr:8
    t = (u32)__builtin_amdgcn_update_dpp(0, (int)r, 0x142, 0xF, 0xF, false);
    r = t > r ? t : r;   // row_bcast:15
    t = (u32)__builtin_amdgcn_update_dpp(0, (int)r, 0x143, 0xF, 0xF, false);
    r = t > r ? t : r;   // row_bcast:31
    return (u32)__builtin_amdgcn_readlane((int)r, 63);  // wave-uniform
}

__device__ __forceinline__ u32 wave_umin_dpp(u32 v) {
    u32 r = v, t;
    t = (u32)__builtin_amdgcn_update_dpp(-1, (int)r, 0x111, 0xF, 0xF, false);
    r = t < r ? t : r;
    t = (u32)__builtin_amdgcn_update_dpp(-1, (int)r, 0x112, 0xF, 0xF, false);
    r = t < r ? t : r;
    t = (u32)__builtin_amdgcn_update_dpp(-1, (int)r, 0x114, 0xF, 0xF, false);
    r = t < r ? t : r;
    t = (u32)__builtin_amdgcn_update_dpp(-1, (int)r, 0x118, 0xF, 0xF, false);
    r = t < r ? t : r;
    t = (u32)__builtin_amdgcn_update_dpp(-1, (int)r, 0x142, 0xF, 0xF, false);
    r = t < r ? t : r;
    t = (u32)__builtin_amdgcn_update_dpp(-1, (int)r, 0x143, 0xF, 0xF, false);
    r = t < r ? t : r;
    return (u32)__builtin_amdgcn_readlane((int)r, 63);  // wave-uniform
}

__global__ __launch_bounds__(256) void greedy_nms_kernel(
    const float* __restrict__ conf,   // [B, NQ]
    const float* __restrict__ pos,    // [B, NQ, 3]
    float* __restrict__ out)          // [B, NUM, 3]
{
    __shared__ float lds[4 * NQ * 3];            // 24 KB: 6 KB per wave
    const int lane = threadIdx.x & 63;
    const int wv   = threadIdx.x >> 6;
    const int b    = (blockIdx.x << 2) | wv;     // grid*4 == B_TOTAL

    const float* cb = conf + (size_t)b * NQ;
    const float* pb = pos  + (size_t)b * NQ * 3;
    float* wl = lds + wv * (NQ * 3);

    // ---- pos: column-major float4 loads (fully coalesced), stage to LDS ----
    const float4* pb4 = reinterpret_cast<const float4*>(pb);
    float4 t0 = pb4[0 * 64 + lane];
    float4 t1 = pb4[1 * 64 + lane];
    float4 t2 = pb4[2 * 64 + lane];
    float4 t3 = pb4[3 * 64 + lane];
    float4 t4 = pb4[4 * 64 + lane];
    float4 t5 = pb4[5 * 64 + lane];

    // ---- conf: column-major dwords; slot i <-> element n = i*64+lane ----
    float c[8];
    #pragma unroll
    for (int i = 0; i < 8; ++i) c[i] = cb[i * 64 + lane];

    float4* wl4 = reinterpret_cast<float4*>(wl);
    wl4[0 * 64 + lane] = t0;
    wl4[1 * 64 + lane] = t1;
    wl4[2 * 64 + lane] = t2;
    wl4[3 * 64 + lane] = t3;
    wl4[4 * 64 + lane] = t4;
    wl4[5 * 64 + lane] = t5;

    // monotone float->u32 keys; key 0 == consumed/failed (no NaN/-inf input)
    u32 k[8];
    #pragma unroll
    for (int i = 0; i < 8; ++i) {
        int bi = __float_as_int(c[i]);
        k[i] = (u32)bi ^ ((u32)(bi >> 31) | 0x80000000u);
    }

    __syncthreads();

    // exact argmax via two DPP reduces; returns wave-uniform element index n
    // and the max key (0 => keys exhausted). Tie-break: min n == reference's
    // stable smaller-index rule (column-major map is order-preserving per
    // lane; min over n handles cross-lane exactly).
    auto argmax_dpp = [&](u32& gm_out) -> int {
        u32 m = k[0];
        #pragma unroll
        for (int i = 1; i < 8; ++i) m = k[i] > m ? k[i] : m;
        const u32 gm = wave_umax_dpp(m);
        int im = 8;
        #pragma unroll
        for (int i = 7; i >= 0; --i)
            if (k[i] == gm) im = i;                 // first equal slot
        const u32 candn = (im < 8) ? (u32)((im << 6) | lane) : 0xFFFFFFFFu;
        const u32 n = wave_umin_dpp(candn);
        gm_out = gm;
        return (int)n;
    };

    auto consume = [&](int n) {
        const int ci = ((n & 63) == lane) ? (n >> 6) : 8;
        #pragma unroll
        for (int i = 0; i < 8; ++i)
            if (ci == i) k[i] = 0u;
    };

    // wave-uniform n -> broadcast LDS read (same addr: conflict-free)
    auto get_row = [&](int n, float& x, float& y, float& z) {
        x = wl[3 * n + 0]; y = wl[3 * n + 1]; z = wl[3 * n + 2];
    };

    const float TH  = 0.78539816339744830961f; // pi/4 (f32 == jnp thresh)
    const float CLO = 0.70710478f;             // cos(pi/4) - ~2e-6
    const float CHI = 0.70710878f;             // cos(pi/4) + ~2e-6

    // zero keys of items failing the angle test vs (px,py,pz); reads are
    // conflict-free: dword index 192i+3*lane -> bank 3*lane mod 32.
    auto mask_keys = [&](float px, float py, float pz) {
        #pragma unroll
        for (int i = 0; i < 8; ++i) {
            const int o = 3 * (i * 64 + lane);
            float x = wl[o + 0], y = wl[o + 1], z = wl[o + 2];
            float d = fabsf(x * px + y * py + z * pz);
            bool pass;
            if (d <= CLO)      pass = true;   // clearly >= pi/4
            else if (d >= CHI) pass = false;  // clearly <  pi/4
            else               pass = (acosf(fminf(d, 1.f)) >= TH); // exact
            if (!pass) k[i] = 0u;
        }
    };

    // ---- #1: global argmax ----
    u32 gm1;
    const int w1 = argmax_dpp(gm1);
    float p1x, p1y, p1z;
    get_row(w1, p1x, p1y, p1z);
    consume(w1);

    // ---- #2: argmax among items passing vs p1 ----
    mask_keys(p1x, p1y, p1z);
    u32 gm2;
    const int w2 = argmax_dpp(gm2);

    float o2x, o2y, o2z, o3x, o3y, o3z;
    if (gm2 != 0u) {                           // wave-uniform
        get_row(w2, o2x, o2y, o2z);
        // ---- #3: additionally pass vs p2 (w2 self-fails: |dot|=1) ----
        mask_keys(o2x, o2y, o2z);
        u32 gm3;
        const int w3 = argmax_dpp(gm3);
        if (gm3 != 0u) {
            get_row(w3, o3x, o3y, o3z);
        } else {
            get_row(0, o3x, o3y, o3z);         // fallback = pos[0]
        }
    } else {
        get_row(0, o2x, o2y, o2z);             // fallback = pos[0]
        o3x = o2x; o3y = o2y; o3z = o2z;
    }

    if (lane == 0) {
        float* ob = out + (size_t)b * 9;
        ob[0] = p1x; ob[1] = p1y; ob[2] = p1z;
        ob[3] = o2x; ob[4] = o2y; ob[5] = o2z;
        ob[6] = o3x; ob[7] = o3y; ob[8] = o3z;
    }
}

extern "C" void kernel_launch(void* const* d_in, const int* in_sizes, int n_in,
                              void* d_out, int out_size, void* d_ws, size_t ws_size,
                              hipStream_t stream) {
    const float* pred_logits = (const float*)d_in[0]; // [B, NQ, 1]
    const float* pred_pos    = (const float*)d_in[1]; // [B, NQ, 3]
    float* out = (float*)d_out;                       // [B, NUM, 3]

    const int grid = B_TOTAL / 4;                     // 4 waves/block
    greedy_nms_kernel<<<grid, 256, 0, stream>>>(pred_logits, pred_pos, out);
}